// Round 1
// baseline (621.901 us; speedup 1.0000x reference)
//
#include <hip/hip_runtime.h>
#include <math.h>

#define S_ 2
#define V_ 4
#define H_ 1024
#define W_ 1024
#define NCELL 65536
#define NSV 8
#define KSEL 1024
#define CROP_LO 102
#define CROP_HI 922
#define NPIX (H_*W_)

static __device__ __forceinline__ unsigned score_key(float score){
  unsigned ub = __float_as_uint(score);
  return (ub & 0x80000000u) ? ~ub : (ub | 0x80000000u);
}

__global__ __launch_bounds__(64) void k_init(unsigned* total){
  if (threadIdx.x == 0) *total = 0u;
}

// One thread per coarse cell (4x4 pixels). Counts alpha>0 within crop, writes
// per-cell count, block-reduces into the global total (exact: integer sum < 2^24).
__global__ __launch_bounds__(256) void k_count(const float* __restrict__ alpha,
                                               unsigned char* __restrict__ cnt,
                                               unsigned* __restrict__ total){
  int g = blockIdx.x * 256 + threadIdx.x;        // 0..524287
  int sv = g >> 16;
  int cell = g & (NCELL - 1);
  int hc = cell >> 8;
  int wc = cell & 255;
  const float4* ap = reinterpret_cast<const float4*>(alpha);
  int c = 0;
  int x0 = wc * 4;
#pragma unroll
  for (int dy = 0; dy < 4; ++dy){
    int y = hc * 4 + dy;
    float4 a = ap[(size_t)(sv * H_ + y) * (W_ / 4) + wc];
    if (y >= CROP_LO && y < CROP_HI){
      c += (a.x > 0.0f) & (x0 + 0 >= CROP_LO) & (x0 + 0 < CROP_HI);
      c += (a.y > 0.0f) & (x0 + 1 >= CROP_LO) & (x0 + 1 < CROP_HI);
      c += (a.z > 0.0f) & (x0 + 2 >= CROP_LO) & (x0 + 2 < CROP_HI);
      c += (a.w > 0.0f) & (x0 + 3 >= CROP_LO) & (x0 + 3 < CROP_HI);
    }
  }
  cnt[g] = (unsigned char)c;
  __shared__ unsigned red[256];
  red[threadIdx.x] = (unsigned)c;
  __syncthreads();
  for (int off = 128; off > 0; off >>= 1){
    if (threadIdx.x < off) red[threadIdx.x] += red[threadIdx.x + off];
    __syncthreads();
  }
  if (threadIdx.x == 0) atomicAdd(total, red[0]);
}

// Per-cell Gumbel-perturbed score -> order-preserving uint key.
__global__ __launch_bounds__(256) void k_score(const unsigned char* __restrict__ cnt,
                                               const float* __restrict__ gum,
                                               const unsigned* __restrict__ total,
                                               unsigned* __restrict__ keys){
  int g = blockIdx.x * 256 + threadIdx.x;
  float T = (float)(*total);
  float denom = __fadd_rn(T, 1e-8f);
  float inv = __fdiv_rn(1.0f, denom);                  // per-pixel probs for mask==1
  const float COFF = (float)((1.0 - 0.9) / (1024.0 * 1024.0)); // (1-ON_MASK)/(H*W)
  float q_on = __fadd_rn(__fmul_rn(0.9f, inv), COFF);  // per-pixel value when mask==1
  int k = cnt[g];
  // probs_c = k*q_on + (16-k)*COFF  (16 pixels per coarse cell)
  float pc = __fadd_rn(__fmul_rn((float)k, q_on), __fmul_rn((float)(16 - k), COFF));
  float logp = logf(__fadd_rn(pc, 1e-9f));
  float u = gum[g];
  float gl = logf(__fadd_rn(u, 1e-9f));
  float gmb = -logf(__fadd_rn(-gl, 1e-9f));
  keys[g] = score_key(__fadd_rn(logp, gmb));
}

// One block per (s,v); thread t owns coarse row t (256 cells, contiguous).
// 4-pass radix select of the 1024th-largest key, exact lowest-index tie fill,
// then in-order emission of uv_s and normalized ray dirs.
__global__ __launch_bounds__(256) void k_select(const unsigned* __restrict__ keys,
                                                const float* __restrict__ uv,
                                                const float* __restrict__ intr,
                                                const float* __restrict__ extr,
                                                const int* __restrict__ fidx,
                                                float* __restrict__ out){
  const int sv = blockIdx.x;
  const int t = threadIdx.x;
  const unsigned* kb = keys + sv * NCELL;
  __shared__ unsigned hist[256];
  __shared__ unsigned scanbuf[256];
  __shared__ unsigned sh_prefix, sh_rem;
  if (t == 0){ sh_prefix = 0u; sh_rem = KSEL; }
  __syncthreads();

  for (int pass = 0; pass < 4; ++pass){
    hist[t] = 0u;
    __syncthreads();
    unsigned pre = sh_prefix;
    int shift = 24 - 8 * pass;
    for (int i = 0; i < 256; ++i){
      unsigned key = kb[t * 256 + i];
      bool ok = true;
      if (pass > 0) ok = (key >> (32 - 8 * pass)) == pre;
      if (ok) atomicAdd(&hist[(key >> shift) & 255u], 1u);
    }
    __syncthreads();
    if (t == 0){
      unsigned rem = sh_rem;
      for (int b = 255; b >= 0; --b){
        unsigned cb = hist[b];
        if (cb >= rem){ sh_prefix = (pre << 8) | (unsigned)b; sh_rem = rem; break; }
        rem -= cb;
      }
    }
    __syncthreads();
  }
  const unsigned thr = sh_prefix;   // exact key value of the 1024th largest
  const unsigned rem = sh_rem;      // how many ==thr to take (lowest indices)

  // per-row counts
  unsigned gt = 0, eq = 0;
  for (int wc = 0; wc < 256; ++wc){
    unsigned key = kb[t * 256 + wc];
    gt += (key > thr);
    eq += (key == thr);
  }
  // exclusive scan of eq across rows (rows are in cell-index order)
  scanbuf[t] = eq; __syncthreads();
  for (int off = 1; off < 256; off <<= 1){
    unsigned x = (t >= off) ? scanbuf[t - off] : 0u;
    __syncthreads();
    scanbuf[t] += x;
    __syncthreads();
  }
  unsigned eqbase = scanbuf[t] - eq;
  unsigned take_eq = 0;
  if (rem > eqbase){ take_eq = rem - eqbase; if (take_eq > eq) take_eq = eq; }
  unsigned m = gt + take_eq;        // selected cells in this coarse row
  __syncthreads();
  // exclusive scan of m -> P (rank base)
  scanbuf[t] = m; __syncthreads();
  for (int off = 1; off < 256; off <<= 1){
    unsigned x = (t >= off) ? scanbuf[t - off] : 0u;
    __syncthreads();
    scanbuf[t] += x;
    __syncthreads();
  }
  unsigned P = scanbuf[t] - m;

  // camera constants
  const int s = sv >> 2;            // V_ == 4
  const float fx = intr[s * 16 + 0];
  const float cx = intr[s * 16 + 2];
  const float fy = intr[s * 16 + 5];
  const float cy = intr[s * 16 + 6];
  const float e00 = extr[sv * 16 + 0], e01 = extr[sv * 16 + 1], e02 = extr[sv * 16 + 2], e03 = extr[sv * 16 + 3];
  const float e10 = extr[sv * 16 + 4], e11 = extr[sv * 16 + 5], e12 = extr[sv * 16 + 6], e13 = extr[sv * 16 + 7];
  const float e20 = extr[sv * 16 + 8], e21 = extr[sv * 16 + 9], e22 = extr[sv * 16 + 10], e23 = extr[sv * 16 + 11];
  const int fi = fidx[sv];
  const int k1 = (fi >> 1) & 1;
  const int k2 = fi & 1;
  if (t < 3) out[sv * 3 + t] = extr[sv * 16 + t * 4 + 3];  // ray_start

  const float* uvx = uv + (size_t)sv * 2 * NPIX;
  const float* uvy = uvx + NPIX;
  float* out_dir = out + S_ * V_ * 3;                     // offset 24
  float* out_uvs = out + S_ * V_ * 3 + S_ * V_ * 4096 * 3; // offset 98328

  unsigned eqr = eqbase;
  unsigned j = 0;
  unsigned baserank = 4u * P;
  for (int wc = 0; wc < 256; ++wc){
    unsigned key = kb[t * 256 + wc];
    bool sel = (key > thr);
    if (key == thr){ if (eqr < rem) sel = true; eqr++; }
    if (!sel) continue;
#pragma unroll
    for (int p1 = 0; p1 < 2; ++p1){
#pragma unroll
      for (int p2 = 0; p2 < 2; ++p2){
        unsigned r = baserank + (unsigned)p1 * 2u * m + 2u * j + (unsigned)p2;
        int y = 4 * t + 2 * p1 + k1;
        int x = 4 * wc + 2 * p2 + k2;
        int flat = y * W_ + x;
        float X = uvx[flat];
        float Y = uvy[flat];
        out_uvs[(sv * 2 + 0) * 4096 + r] = X;
        out_uvs[(sv * 2 + 1) * 4096 + r] = Y;
        float xx = (X - cx) / fx;
        float yy = (Y - cy) / fy;
        float d0 = (e00 * xx + e01 * yy + e02 + e03) - e03;
        float d1 = (e10 * xx + e11 * yy + e12 + e13) - e13;
        float d2 = (e20 * xx + e21 * yy + e22 + e23) - e23;
        float nrm = sqrtf(d0 * d0 + d1 * d1 + d2 * d2);
        float den = fmaxf(nrm, 1e-12f);
        size_t ob = ((size_t)sv * 4096 + r) * 3;
        out_dir[ob + 0] = d0 / den;
        out_dir[ob + 1] = d1 / den;
        out_dir[ob + 2] = d2 / den;
      }
    }
    j++;
  }
}

extern "C" void kernel_launch(void* const* d_in, const int* in_sizes, int n_in,
                              void* d_out, int out_size, void* d_ws, size_t ws_size,
                              hipStream_t stream){
  (void)in_sizes; (void)n_in; (void)out_size; (void)ws_size;
  const float* uv         = (const float*)d_in[0];
  const float* intr       = (const float*)d_in[1];
  const float* extr       = (const float*)d_in[2];
  const float* alpha      = (const float*)d_in[3];
  const float* gum        = (const float*)d_in[5];
  const int*   full_index = (const int*)d_in[6];
  float* out = (float*)d_out;

  unsigned*      total = (unsigned*)d_ws;
  unsigned char* cnt   = (unsigned char*)d_ws + 4096;
  unsigned*      keys  = (unsigned*)((char*)d_ws + 4096 + NSV * NCELL); // u8 counts end here

  hipLaunchKernelGGL(k_init,  dim3(1),                 dim3(64),  0, stream, total);
  hipLaunchKernelGGL(k_count, dim3(NSV * NCELL / 256), dim3(256), 0, stream, alpha, cnt, total);
  hipLaunchKernelGGL(k_score, dim3(NSV * NCELL / 256), dim3(256), 0, stream, cnt, gum, total, keys);
  hipLaunchKernelGGL(k_select,dim3(NSV),               dim3(256), 0, stream, keys, uv, intr, extr, full_index, out);
}